// Round 1
// baseline (741.911 us; speedup 1.0000x reference)
//
#include <hip/hip_runtime.h>
#include <math.h>

#define BB 32
#define SS 4096
#define HH 1024

// Kernel A: v[b,h] = sum_k hidden[b,k] * W[k,h]
// Grid (HH/256, BB), block 256. Coalesced along h; hidden[b,k] is wave-uniform.
__global__ __launch_bounds__(256) void compute_v_kernel(
        const float* __restrict__ hidden,
        const float* __restrict__ W,
        float* __restrict__ v) {
    const int b = blockIdx.y;
    const int h = blockIdx.x * 256 + threadIdx.x;
    const float* __restrict__ hb = hidden + b * HH;
    float acc = 0.f;
#pragma unroll 8
    for (int k = 0; k < HH; ++k) {
        acc = fmaf(hb[k], W[(size_t)k * HH + h], acc);
    }
    v[b * HH + h] = acc;
}

// Kernel B: scores[b,s] = dot(enc[b,s,:], v[b,:]).
// One wave per s. Each lane: 4x float4 -> 16 elements -> 64 lanes * 16 = 1024 = HH.
// Grid (SS/4, BB), block 256 (4 waves).
__global__ __launch_bounds__(256) void compute_scores_kernel(
        const float* __restrict__ enc,
        const float* __restrict__ v,
        float* __restrict__ scores) {
    const int b = blockIdx.y;
    const int wave = threadIdx.x >> 6;
    const int lane = threadIdx.x & 63;
    const int s = blockIdx.x * 4 + wave;

    const float4* __restrict__ e4 =
        (const float4*)(enc + ((size_t)b * SS + s) * HH);
    const float4* __restrict__ v4 = (const float4*)(v + b * HH);

    float acc = 0.f;
#pragma unroll
    for (int i = 0; i < 4; ++i) {
        float4 e = e4[i * 64 + lane];
        float4 w = v4[i * 64 + lane];
        acc += e.x * w.x + e.y * w.y + e.z * w.z + e.w * w.w;
    }
#pragma unroll
    for (int off = 32; off > 0; off >>= 1)
        acc += __shfl_down(acc, off, 64);
    if (lane == 0) scores[(size_t)b * SS + s] = acc;
}

// Kernel C: in-place softmax over S per batch row. One block per b, 256 threads,
// 16 elements per thread. (The hidden.bias constant cancels in softmax exactly,
// so it is omitted upstream.)
__global__ __launch_bounds__(256) void softmax_kernel(float* __restrict__ scores) {
    const int b = blockIdx.x;
    float* __restrict__ row = scores + (size_t)b * SS;
    const int tid = threadIdx.x;
    const int lane = tid & 63;
    const int wave = tid >> 6;

    __shared__ float red_max[4];
    __shared__ float red_sum[4];

    float vals[16];
    float m = -INFINITY;
#pragma unroll
    for (int i = 0; i < 16; ++i) {
        vals[i] = row[i * 256 + tid];
        m = fmaxf(m, vals[i]);
    }
#pragma unroll
    for (int off = 32; off > 0; off >>= 1)
        m = fmaxf(m, __shfl_down(m, off, 64));
    if (lane == 0) red_max[wave] = m;
    __syncthreads();
    m = fmaxf(fmaxf(red_max[0], red_max[1]), fmaxf(red_max[2], red_max[3]));

    float sum = 0.f;
#pragma unroll
    for (int i = 0; i < 16; ++i) {
        vals[i] = __expf(vals[i] - m);
        sum += vals[i];
    }
#pragma unroll
    for (int off = 32; off > 0; off >>= 1)
        sum += __shfl_down(sum, off, 64);
    if (lane == 0) red_sum[wave] = sum;
    __syncthreads();
    sum = red_sum[0] + red_sum[1] + red_sum[2] + red_sum[3];

    const float inv = 1.f / sum;
#pragma unroll
    for (int i = 0; i < 16; ++i)
        row[i * 256 + tid] = vals[i] * inv;
}

extern "C" void kernel_launch(void* const* d_in, const int* in_sizes, int n_in,
                              void* d_out, int out_size, void* d_ws, size_t ws_size,
                              hipStream_t stream) {
    const float* hidden = (const float*)d_in[0];   // [B,1,H]
    const float* enc    = (const float*)d_in[1];   // [B,S,H]
    const float* W      = (const float*)d_in[2];   // [H,H]
    // d_in[3] = bias[H]: contributes a per-b constant to the logits which
    // cancels exactly in softmax -> unused.
    float* out = (float*)d_out;                    // [B,S] fp32
    float* v   = (float*)d_ws;                     // [B,H] scratch (128 KiB)

    compute_v_kernel<<<dim3(HH / 256, BB), 256, 0, stream>>>(hidden, W, v);
    compute_scores_kernel<<<dim3(SS / 4, BB), 256, 0, stream>>>(enc, v, out);
    softmax_kernel<<<BB, 256, 0, stream>>>(out);
}

// Round 2
// 689.535 us; speedup vs baseline: 1.0760x; 1.0760x over previous
//
#include <hip/hip_runtime.h>
#include <math.h>

#define BB 32
#define SS 4096
#define HH 1024

typedef float fvec4 __attribute__((ext_vector_type(4)));

// Kernel A: v[b,h] = sum_k hidden[b,k] * W[k,h], 8-way k-split + atomicAdd.
// Grid (HH/256, BB, 8), block 256. Coalesced along h; short (128) k-chains
// so load latency doesn't serialize. v must be zeroed first (memsetAsync).
__global__ __launch_bounds__(256) void compute_v_kernel(
        const float* __restrict__ hidden,
        const float* __restrict__ W,
        float* __restrict__ v) {
    const int b = blockIdx.y;
    const int h = blockIdx.x * 256 + threadIdx.x;
    const int k0 = blockIdx.z * 128;
    const float* __restrict__ hb = hidden + b * HH + k0;
    const float* __restrict__ Wp = W + (size_t)k0 * HH + h;
    float acc = 0.f;
#pragma unroll 8
    for (int k = 0; k < 128; ++k)
        acc = fmaf(hb[k], Wp[(size_t)k * HH], acc);
    atomicAdd(&v[b * HH + h], acc);
}

// Kernel B: scores[b,s] = dot(enc[b,s,:], v[b,:]).
// One wave handles 4 consecutive s rows; v[b] loaded into registers once per
// wave and reused 4x. 16 independent float4 enc loads in flight per lane.
// Grid (SS/16, BB), block 256 (4 waves -> 16 s per block).
__global__ __launch_bounds__(256) void compute_scores_kernel(
        const float* __restrict__ enc,
        const float* __restrict__ v,
        float* __restrict__ scores) {
    const int b = blockIdx.y;
    const int wave = threadIdx.x >> 6;
    const int lane = threadIdx.x & 63;
    const int s0 = (blockIdx.x * 4 + wave) * 4;

    const fvec4* __restrict__ v4 = (const fvec4*)(v + b * HH);
    const fvec4 w0 = v4[lane];
    const fvec4 w1 = v4[64 + lane];
    const fvec4 w2 = v4[128 + lane];
    const fvec4 w3 = v4[192 + lane];

    const fvec4* __restrict__ e4 =
        (const fvec4*)(enc + ((size_t)b * SS + s0) * HH);

    float acc[4];
#pragma unroll
    for (int j = 0; j < 4; ++j) {
        const fvec4* __restrict__ p = e4 + (size_t)j * 256;
        fvec4 e0 = p[lane];
        fvec4 e1 = p[64 + lane];
        fvec4 e2 = p[128 + lane];
        fvec4 e3 = p[192 + lane];
        fvec4 t = e0 * w0 + e1 * w1 + e2 * w2 + e3 * w3;
        acc[j] = t.x + t.y + t.z + t.w;
    }
#pragma unroll
    for (int j = 0; j < 4; ++j) {
#pragma unroll
        for (int off = 32; off > 0; off >>= 1)
            acc[j] += __shfl_xor(acc[j], off, 64);
    }
    if (lane == 0) {
        fvec4 r = {acc[0], acc[1], acc[2], acc[3]};
        *(fvec4*)(scores + (size_t)b * SS + s0) = r;
    }
}

// Kernel C: in-place softmax over S per batch row. One block per b,
// 1024 threads, 4 elements each. (hidden.bias logit constant cancels in
// softmax exactly, so it is omitted upstream.)
__global__ __launch_bounds__(1024) void softmax_kernel(float* __restrict__ scores) {
    const int b = blockIdx.x;
    float* __restrict__ row = scores + (size_t)b * SS;
    const int tid = threadIdx.x;
    const int lane = tid & 63;
    const int wave = tid >> 6;   // 16 waves

    __shared__ float red_max[16];
    __shared__ float red_sum[16];

    float vals[4];
    float m = -INFINITY;
#pragma unroll
    for (int i = 0; i < 4; ++i) {
        vals[i] = row[i * 1024 + tid];
        m = fmaxf(m, vals[i]);
    }
#pragma unroll
    for (int off = 32; off > 0; off >>= 1)
        m = fmaxf(m, __shfl_xor(m, off, 64));
    if (lane == 0) red_max[wave] = m;
    __syncthreads();
#pragma unroll
    for (int i = 0; i < 16; ++i) m = fmaxf(m, red_max[i]);

    float sum = 0.f;
#pragma unroll
    for (int i = 0; i < 4; ++i) {
        vals[i] = __expf(vals[i] - m);
        sum += vals[i];
    }
#pragma unroll
    for (int off = 32; off > 0; off >>= 1)
        sum += __shfl_xor(sum, off, 64);
    if (lane == 0) red_sum[wave] = sum;
    __syncthreads();
    sum = 0.f;
#pragma unroll
    for (int i = 0; i < 16; ++i) sum += red_sum[i];

    const float inv = 1.f / sum;
#pragma unroll
    for (int i = 0; i < 4; ++i)
        row[i * 1024 + tid] = vals[i] * inv;
}

extern "C" void kernel_launch(void* const* d_in, const int* in_sizes, int n_in,
                              void* d_out, int out_size, void* d_ws, size_t ws_size,
                              hipStream_t stream) {
    const float* hidden = (const float*)d_in[0];   // [B,1,H]
    const float* enc    = (const float*)d_in[1];   // [B,S,H]
    const float* W      = (const float*)d_in[2];   // [H,H]
    // d_in[3] = bias[H]: contributes a per-b constant to the logits which
    // cancels exactly in softmax -> unused.
    float* out = (float*)d_out;                    // [B,S] fp32
    float* v   = (float*)d_ws;                     // [B,H] scratch (128 KiB)

    hipMemsetAsync(v, 0, (size_t)BB * HH * sizeof(float), stream);
    compute_v_kernel<<<dim3(HH / 256, BB, 8), 256, 0, stream>>>(hidden, W, v);
    compute_scores_kernel<<<dim3(SS / 16, BB), 256, 0, stream>>>(enc, v, out);
    softmax_kernel<<<BB, 1024, 0, stream>>>(out);
}